// Round 9
// baseline (115.671 us; speedup 1.0000x reference)
//
#include <hip/hip_runtime.h>
#include <math.h>

// AetherSparcNet round 9 — single heterogeneous dispatch, zero LDS.
// R6 retry with its three failure causes removed:
//  (a) R6 reserved 64KB LDS in every block -> 2 blocks/CU ceiling. Now NO
//      LDS: builders read W2 rows from per-XCD L2 (wave-coalesced float4,
//      row broadcast across the 4 lane-groups; 64KB resident per XCD).
//  (b) R6 had 32 agent-bypass table loads per thread (ITEMS=16). Now 4
//      (ITEMS=2) at ~20 waves/CU -> latency overlapped.
//  (c) scanner grid 2048 thin blocks (R8-proven), not 256 fat ones.
// Blocks 0..255: build 32 table entries each (s=16 k-split, E=2, merged
//   dual-entry butterfly); table entries stored with relaxed agent stores
//   (write-through to IF$); __syncthreads drains; t0 release-stores flag=1.
// Blocks 256..2303: R8 kS verbatim (mask, wave scan, exact backward
//   lookback — mask ~97.5% dense so expected 1 iter; publish cnt relaxed
//   agent, +1 encoding, 0xAA poison = not-ready), THEN poll 256 builder
//   flags (1/thread), THEN epilogue with table reads as relaxed agent
//   loads (IF$ direct; no acquire fence -> x/out stay cache-warm).
// Scanner block 0 alone gathers the 2048 cnts -> out[n] = n_active.
// No deadlock: builders wait on nobody; they are blocks 0..255 (dispatched
// first); spinners s_sleep. Graph replays are value-benign.

#define THRESH   0.045f
#define NH       128
#define TSZ      8192
#define GMIN     -6.0f
#define GMAX     6.0f
#define TPB      256
#define ITEMS    2
#define CHUNK    (TPB * ITEMS)   // 512
#define NBUILD   256             // builder blocks, 32 entries each
#define NSCAN    2048            // 1M / 512
#define POISON32 0xAAAAAAAAu

__global__ __launch_bounds__(TPB) void kF(const float* __restrict__ x, int n,
                                          const float* __restrict__ W1,
                                          const float* __restrict__ b1,
                                          const float* __restrict__ W2,
                                          const float* __restrict__ b2,
                                          const float* __restrict__ W3,
                                          const float* __restrict__ b3,
                                          float* __restrict__ table,
                                          unsigned int* __restrict__ cnts,
                                          unsigned int* __restrict__ tflag,
                                          float* __restrict__ out) {
  const int t = threadIdx.x, b = blockIdx.x;
  const int lane = t & 63, wv = t >> 6;

  if (b < NBUILD) {
    // ================= builder (no LDS; W2 rows from L2) =================
    const int p  = t & 15;                  // lane in 16-lane group
    const int e0 = b * 32 + (t >> 4) * 2;   // 16 groups x 2 entries
    const float step = (GMAX - GMIN) * (1.0f / (float)(TSZ - 1));
    const float xv0 = GMIN + step * (float)e0;
    const float xv1 = xv0 + step;

    // lane p owns k in {4*(p+16c)+r : c<2, r<4}
    float h10[8], h11[8];
    #pragma unroll
    for (int c = 0; c < 2; ++c) {
      #pragma unroll
      for (int r = 0; r < 4; ++r) {
        const int k = 4 * (p + 16 * c) + r;
        const float w = W1[k], bb = b1[k];
        h10[c * 4 + r] = fmaxf(fmaf(xv0, w, bb), 0.0f);
        h11[c * 4 + r] = fmaxf(fmaf(xv1, w, bb), 0.0f);
      }
    }
    const bool hi = (p & 8) != 0;
    float y = 0.0f;                 // lo half-group -> e0, hi -> e1
    const float b3v = b3[0];
    #pragma unroll 2
    for (int j = 0; j < NH; ++j) {
      const float* row = &W2[j * NH];
      float a0 = 0.f, a1 = 0.f, c0 = 0.f, c1 = 0.f;
      #pragma unroll
      for (int c = 0; c < 2; ++c) {
        const float4 w = *(const float4*)&row[4 * (p + 16 * c)];
        a0 = fmaf(h10[c * 4 + 0], w.x, a0);
        a1 = fmaf(h10[c * 4 + 1], w.y, a1);
        a0 = fmaf(h10[c * 4 + 2], w.z, a0);
        a1 = fmaf(h10[c * 4 + 3], w.w, a1);
        c0 = fmaf(h11[c * 4 + 0], w.x, c0);
        c1 = fmaf(h11[c * 4 + 1], w.y, c1);
        c0 = fmaf(h11[c * 4 + 2], w.z, c0);
        c1 = fmaf(h11[c * 4 + 3], w.w, c1);
      }
      const float s0 = a0 + a1, s1 = c0 + c1;
      float u = hi ? s1 : s0;
      float v = hi ? s0 : s1;
      v = __shfl_xor(v, 8);
      u += v;
      u += __shfl_xor(u, 1);
      u += __shfl_xor(u, 2);
      u += __shfl_xor(u, 4);
      const float h2 = fmaxf(u + b2[j], 0.0f);
      y = fmaf(h2, W3[j], y);
    }
    if ((p & 7) == 0)
      __hip_atomic_store(&table[e0 + (p >> 3)], y + b3v,
                         __ATOMIC_RELAXED, __HIP_MEMORY_SCOPE_AGENT);
    __syncthreads();   // drain all waves' table stores (vmcnt 0 at barrier)
    if (t == 0)
      __hip_atomic_store(&tflag[b], 1u, __ATOMIC_RELEASE,
                         __HIP_MEMORY_SCOPE_AGENT);
    return;
  }

  // ================= scanner (R8 kS + flag poll) =================
  __shared__ int swl[4], swc[4], sred[4];
  __shared__ int sgx;
  const int s = b - NBUILD;                // 0..2047
  const int base = s * CHUNK + t * ITEMS;

  float xs[ITEMS];
  const bool full = (base + ITEMS) <= n;
  if (full) {
    const float2 v = *(const float2*)(x + base);
    xs[0] = v.x; xs[1] = v.y;
  } else {
    #pragma unroll
    for (int it = 0; it < ITEMS; ++it)
      xs[it] = (base + it < n) ? x[base + it] : 0.0f;
  }
  float prev = (base > 0 && base <= n) ? x[base - 1] : 0.0f;
  unsigned m = 0; int tl = -1; int cnt = 0;
  #pragma unroll
  for (int it = 0; it < ITEMS; ++it) {
    const int i = base + it;
    if (i < n) {
      const bool act = (i == 0) || (fabsf(xs[it] - prev) > THRESH);
      if (act) { tl = i; ++cnt; m |= (1u << it); }
      prev = xs[it];
    }
  }

  int incl = tl;
  #pragma unroll
  for (int off = 1; off < 64; off <<= 1) {
    const int v = __shfl_up(incl, off);
    if (lane >= off) incl = max(incl, v);
  }
  int wsum = cnt;
  #pragma unroll
  for (int off = 1; off < 64; off <<= 1) wsum += __shfl_xor(wsum, off);
  if (lane == 63) swl[wv] = incl;
  if (lane == 0)  swc[wv] = wsum;

  // wave 0: exact backward lookback for block prefix
  if (wv == 0) {
    int g = -1;
    if (s > 0) {
      int ws = s * CHUNK - 64;
      for (;;) {
        const int i = ws + lane;
        const float xi = x[i];
        const float xp = (i > 0) ? x[i - 1] : 0.0f;
        const bool act = (i == 0) || (fabsf(xi - xp) > THRESH);
        const unsigned long long bal = __ballot(act);
        if (bal) { g = ws + 63 - (int)__builtin_clzll(bal); break; }
        ws -= 64;   // terminates: element 0 forced active
      }
    }
    if (lane == 0) sgx = g;
  }
  __syncthreads();

  const int exclW = __shfl_up(incl, 1);
  int run = sgx;
  #pragma unroll
  for (int w = 0; w < 4; ++w) if (w < wv) run = max(run, swl[w]);
  if (lane > 0) run = max(run, exclW);

  // publish block count (self-contained; relaxed agent)
  if (t == 0) {
    const int bcnt = swc[0] + swc[1] + swc[2] + swc[3];
    __hip_atomic_store(&cnts[s], (unsigned)(bcnt + 1),
                       __ATOMIC_RELAXED, __HIP_MEMORY_SCOPE_AGENT);
  }

  // poll builder flags: thread t owns flag t (256 flags, 256 threads)
  {
    for (;;) {
      const unsigned f = __hip_atomic_load(&tflag[t], __ATOMIC_RELAXED,
                                           __HIP_MEMORY_SCOPE_AGENT);
      if (f == 1u) break;
      __builtin_amdgcn_s_sleep(2);
    }
  }
  __syncthreads();   // all 256 flags confirmed block-wide

  // epilogue: lerp + decay; table via agent-scope IF$ loads (4/thread)
  const float invstep = (float)(TSZ - 1) / (GMAX - GMIN);
  if (full) {
    float o[ITEMS];
    #pragma unroll
    for (int it = 0; it < ITEMS; ++it) {
      const int i = base + it;
      const bool act = (m >> it) & 1u;
      if (act) run = i;
      const float xj = act ? xs[it] : x[run];
      const float u = (xj - GMIN) * invstep;
      int i0 = (int)u;
      i0 = max(0, min(i0, TSZ - 2));
      const float f = u - (float)i0;
      const float t0 = __hip_atomic_load(&table[i0], __ATOMIC_RELAXED,
                                         __HIP_MEMORY_SCOPE_AGENT);
      const float t1 = __hip_atomic_load(&table[i0 + 1], __ATOMIC_RELAXED,
                                         __HIP_MEMORY_SCOPE_AGENT);
      o[it] = fmaf(f, t1 - t0, t0) * __expf((float)(run - i) * 0.05f);
    }
    float2 ov = { o[0], o[1] };
    *(float2*)(out + base) = ov;
  } else {
    #pragma unroll
    for (int it = 0; it < ITEMS; ++it) {
      const int i = base + it;
      if (i >= n) break;
      const bool act = (m >> it) & 1u;
      if (act) run = i;
      const float xj = act ? xs[it] : x[run];
      const float u = (xj - GMIN) * invstep;
      int i0 = (int)u;
      i0 = max(0, min(i0, TSZ - 2));
      const float f = u - (float)i0;
      const float t0 = __hip_atomic_load(&table[i0], __ATOMIC_RELAXED,
                                         __HIP_MEMORY_SCOPE_AGENT);
      const float t1 = __hip_atomic_load(&table[i0 + 1], __ATOMIC_RELAXED,
                                         __HIP_MEMORY_SCOPE_AGENT);
      out[i] = fmaf(f, t1 - t0, t0) * __expf((float)(run - i) * 0.05f);
    }
  }

  // scanner block 0 only: gather n_active (no other block waits)
  if (s == 0) {
    int v = 0;
    #pragma unroll
    for (int s8 = 0; s8 < NSCAN / TPB; ++s8) {   // 8 slots/thread
      const int idx = t + s8 * TPB;
      unsigned c;
      for (;;) {
        c = __hip_atomic_load(&cnts[idx], __ATOMIC_RELAXED,
                              __HIP_MEMORY_SCOPE_AGENT);
        if (c != POISON32) break;
        __builtin_amdgcn_s_sleep(2);
      }
      v += (int)c - 1;
    }
    #pragma unroll
    for (int off = 1; off < 64; off <<= 1) v += __shfl_xor(v, off);
    if (lane == 0) sred[wv] = v;
    __syncthreads();
    if (t == 0) out[n] = (float)(sred[0] + sred[1] + sred[2] + sred[3]);
  }
}

extern "C" void kernel_launch(void* const* d_in, const int* in_sizes, int n_in,
                              void* d_out, int out_size, void* d_ws, size_t ws_size,
                              hipStream_t stream) {
  const float* x  = (const float*)d_in[0];
  const float* W1 = (const float*)d_in[1];
  const float* b1 = (const float*)d_in[2];
  const float* W2 = (const float*)d_in[3];
  const float* b2 = (const float*)d_in[4];
  const float* W3 = (const float*)d_in[5];
  const float* b3 = (const float*)d_in[6];
  float* out = (float*)d_out;
  const int n = in_sizes[0];                   // 1048576 = NSCAN * CHUNK

  char* w = (char*)d_ws;
  float* table = (float*)w;                                // 32 KB
  unsigned int* cnts  = (unsigned int*)(w + TSZ * 4);      // 8 KB
  unsigned int* tflag = (unsigned int*)(w + TSZ * 4 + NSCAN * 4); // 1 KB

  kF<<<NBUILD + NSCAN, TPB, 0, stream>>>(x, n, W1, b1, W2, b2, W3, b3,
                                         table, cnts, tflag, out);
}